// Round 12
// baseline (267.846 us; speedup 1.0000x reference)
//
#include <hip/hip_runtime.h>
#include <hip/hip_bf16.h>
#include <math.h>

#define G_GENES 2000
#define C_CELLS 128
#define H_DIM   256
#define CE_DIM  64
#define LDAe    260   // x1t row stride (bf16 elems): 130 dw = 2 mod 32 -> conflict-free

typedef __attribute__((ext_vector_type(8))) short short8;
typedef __attribute__((ext_vector_type(4))) float floatx4;

__device__ __forceinline__ float eluf(float x) {
    float e = __expf(x) - 1.0f;
    return x > 0.0f ? x : e;
}
__device__ __forceinline__ unsigned short f2bf(float v) {
    unsigned u = __float_as_uint(v);
    u += 0x7FFF + ((u >> 16) & 1);       // RNE
    return (unsigned short)(u >> 16);
}
__device__ __forceinline__ unsigned pk2(float a, float b) {   // v_cvt_pk_bf16_f32
    __hip_bfloat162 h2 = __float22bfloat162_rn(make_float2(a, b));
    unsigned r; __builtin_memcpy(&r, &h2, 4); return r;
}
__device__ __forceinline__ float bflo(unsigned u) { return __uint_as_float(u << 16); }
__device__ __forceinline__ float bfhi(unsigned u) { return __uint_as_float(u & 0xffff0000u); }
union U8 { unsigned u[4]; short8 s; uint4 v; };

// ---------------------------------------------------------------------------
// K_g1: 2056 blocks x 512 threads, four roles (unchanged from R10):
//  [0,1024):     fp32 split-K hid partials
//  [1024,1040):  w2abt[n][k] = bf16(g_w2[k][n]), k<256
//  [1040,1056):  w2bb[h][j]  = bf16(g_w2[256+h][j])
//  [1056,2056):  Bvg[g][h] per-gene bias row (2 genes/block)
// ---------------------------------------------------------------------------
__global__ __launch_bounds__(512) void k_g1(
    const float* __restrict__ ctrl, const float* __restrict__ ce_w1,
    const float* __restrict__ g_w1, const float* __restrict__ g_b1,
    const float* __restrict__ shiftv, const int* __restrict__ gidx,
    const float* __restrict__ gtab, const float* __restrict__ g_w2,
    float* __restrict__ hidpart, unsigned short* __restrict__ w2abt,
    unsigned short* __restrict__ w2bb, float* __restrict__ Bvg)
{
    const int b = blockIdx.x;
    const int t = threadIdx.x;

    if (b < 1024) {
        __shared__ float crow[2][128];
        const int cpair = b >> 4;
        const int kc    = b & 15;
        const int csub  = t >> 8;
        const int h     = t & 255;
        const int c     = cpair * 2 + csub;

        if (h < 125) crow[csub][h] = ctrl[(size_t)c * G_GENES + kc * 125 + h];
        __syncthreads();

        float s0 = 0.f, s1 = 0.f, s2 = 0.f, s3 = 0.f, s4 = 0.f;
        const float* w = ce_w1 + (size_t)(kc * 125) * H_DIM + h;
        const float* cr = crow[csub];
        #pragma unroll 5
        for (int k = 0; k < 125; k += 5) {
            s0 = fmaf(cr[k + 0], w[(size_t)(k + 0) * H_DIM], s0);
            s1 = fmaf(cr[k + 1], w[(size_t)(k + 1) * H_DIM], s1);
            s2 = fmaf(cr[k + 2], w[(size_t)(k + 2) * H_DIM], s2);
            s3 = fmaf(cr[k + 3], w[(size_t)(k + 3) * H_DIM], s3);
            s4 = fmaf(cr[k + 4], w[(size_t)(k + 4) * H_DIM], s4);
        }
        hidpart[((size_t)kc * C_CELLS + c) * H_DIM + h] = ((s0 + s1) + (s2 + s3)) + s4;
    } else if (b < 1040) {
        const int n  = (b - 1024) * 16 + (t >> 5);
        const int k0 = (t & 31) * 8;
        float v[8];
        #pragma unroll
        for (int j = 0; j < 8; ++j) v[j] = g_w2[(size_t)(k0 + j) * H_DIM + n];
        U8 u;
        u.u[0] = pk2(v[0], v[1]); u.u[1] = pk2(v[2], v[3]);
        u.u[2] = pk2(v[4], v[5]); u.u[3] = pk2(v[6], v[7]);
        *(uint4*)&w2abt[(size_t)n * H_DIM + k0] = u.v;
    } else if (b < 1056) {
        const int hr = (b - 1040) * 16 + (t >> 5);
        const int j0 = (t & 31) * 8;
        const float* src = g_w2 + (size_t)(H_DIM + hr) * H_DIM + j0;
        float4 f0 = *(const float4*)src;
        float4 f1 = *(const float4*)(src + 4);
        U8 u;
        u.u[0] = pk2(f0.x, f0.y); u.u[1] = pk2(f0.z, f0.w);
        u.u[2] = pk2(f1.x, f1.y); u.u[3] = pk2(f1.z, f1.w);
        *(uint4*)&w2bb[(size_t)hr * H_DIM + j0] = u.v;
    } else {
        const int g = (b - 1056) * 2 + (t >> 8);
        const int h = t & 255;
        const int idx = gidx[g];
        float bv = g_b1[h] + 128.0f * g_w1[(size_t)130 * H_DIM + h]
                 + shiftv[idx] * g_w1[(size_t)129 * H_DIM + h];
        #pragma unroll 8
        for (int e = 0; e < CE_DIM; ++e)
            bv = fmaf(gtab[(size_t)idx * CE_DIM + e], g_w1[(size_t)(65 + e) * H_DIM + h], bv);
        Bvg[(size_t)g * H_DIM + h] = bv;
    }
}

// ---------------------------------------------------------------------------
// K_fin: 128 blocks x 256 thr (unchanged from R10)
// ---------------------------------------------------------------------------
__global__ __launch_bounds__(256) void k_fin(
    const float* __restrict__ hidpart, const float* __restrict__ ce_b1,
    const float* __restrict__ ce_w2, const float* __restrict__ ce_b2,
    const float* __restrict__ g_w1, unsigned short* __restrict__ Atcbf)
{
    __shared__ float hid[H_DIM];
    __shared__ float celp[4 * CE_DIM];
    __shared__ float cel[CE_DIM];
    const int c = blockIdx.x;
    const int t = threadIdx.x;

    float s = ce_b1[t];
    #pragma unroll
    for (int kc = 0; kc < 16; ++kc)
        s += hidpart[((size_t)kc * C_CELLS + c) * H_DIM + t];
    hid[t] = eluf(s);
    __syncthreads();

    {
        const int e = t & 63, q4 = t >> 6;
        float cp = 0.f;
        #pragma unroll 8
        for (int hh = 0; hh < 64; ++hh)
            cp = fmaf(hid[q4 * 64 + hh], ce_w2[(size_t)(q4 * 64 + hh) * CE_DIM + e], cp);
        celp[q4 * CE_DIM + e] = cp;
    }
    __syncthreads();
    if (t < CE_DIM)
        cel[t] = ce_b2[t] + celp[t] + celp[CE_DIM + t] + celp[2 * CE_DIM + t] + celp[3 * CE_DIM + t];
    __syncthreads();

    float a = 0.f;
    #pragma unroll 8
    for (int e = 0; e < CE_DIM; ++e) a = fmaf(cel[e], g_w1[(size_t)(1 + e) * H_DIM + t], a);
    Atcbf[(size_t)c * H_DIM + t] = f2bf(a);
}

// ---------------------------------------------------------------------------
// K_main: TWO genes SEQUENTIALLY per block (no overlapping acc sets -> no
// spill), 512 threads = 8 waves (2m x 4n). Per gene: R10's exact phase
// pipeline, with softmax max-subtraction removed (logits ~ +-0.01; clamped
// at 80 for insurance) -> 6 barriers/gene + shared B0.
// ---------------------------------------------------------------------------
__global__ __launch_bounds__(512, 4) void k_main(
    const float* __restrict__ ctrl, const int* __restrict__ gidx,
    const float* __restrict__ g_w1, const float* __restrict__ g_b2,
    const float* __restrict__ g_w3, const unsigned short* __restrict__ Atcbf,
    const float* __restrict__ Bvg, const unsigned short* __restrict__ w2abt,
    const unsigned short* __restrict__ w2bb, float* __restrict__ out)
{
    __shared__ __align__(16) unsigned short x1t[C_CELLS * LDAe];  // 66560 B
    __shared__ __align__(16) float scratch[8 * 258];              // pp -> red2
    __shared__ float pvec[H_DIM];
    __shared__ float qtmp[H_DIM];
    __shared__ float qv[H_DIM];
    __shared__ float w3v[H_DIM];
    __shared__ float cc2[2][C_CELLS];
    __shared__ float wred[2];

    const int g0i = blockIdx.x * 2;
    const int t = threadIdx.x;

    const int lane = t & 63;
    const int w    = t >> 6;
    const int quad = lane >> 4;
    const int nlo  = lane & 15;
    const int wm   = w >> 2;
    const int wn   = w & 3;
    const int ho = t & 31, cgrp = t >> 5;
    const int h0 = ho * 8;

    // ---- pre-B0 prefetches (gene 0) ----
    uint4 A[8];
    #pragma unroll
    for (int i = 0; i < 8; ++i)
        A[i] = *(const uint4*)(Atcbf + (size_t)(cgrp * 8 + i) * H_DIM + h0);
    float4 bva = *(const float4*)(Bvg + (size_t)g0i * H_DIM + h0);
    float4 bvb = *(const float4*)(Bvg + (size_t)g0i * H_DIM + h0 + 4);
    float4 wv0 = *(const float4*)(g_w1 + h0);
    float4 wv1 = *(const float4*)(g_w1 + h0 + 4);

    const unsigned short* bbase = w2abt + (size_t)(wn * 64 + nlo) * H_DIM + quad * 8;
    short8 bcur[4];
    #pragma unroll
    for (int nt = 0; nt < 4; ++nt)
        bcur[nt] = *(const short8*)(bbase + (size_t)nt * 16 * H_DIM);

    if (t < C_CELLS) {
        cc2[0][t] = ctrl[(size_t)t * G_GENES + gidx[g0i]];
        cc2[1][t] = ctrl[(size_t)t * G_GENES + gidx[g0i + 1]];
    }
    if (t < H_DIM) w3v[t] = g_w3[t];
    __syncthreads();   // B0

    const unsigned short* abase = &x1t[(wm * 64 + nlo) * LDAe + quad * 8];
    float* red2 = scratch;

    #pragma unroll 1
    for (int gg = 0; gg < 2; ++gg) {
        const float* cc = cc2[gg];

        // ===== x1 build (+ register p-partials) =====
        {
            float s[8];
            #pragma unroll
            for (int j = 0; j < 8; ++j) s[j] = 0.f;
            #pragma unroll
            for (int i = 0; i < 8; ++i) {
                const int c = cgrp * 8 + i;
                const float ccv = cc[c];
                float v0 = eluf(fmaf(ccv, wv0.x, bflo(A[i].x) + bva.x));
                float v1 = eluf(fmaf(ccv, wv0.y, bfhi(A[i].x) + bva.y));
                float v2 = eluf(fmaf(ccv, wv0.z, bflo(A[i].y) + bva.z));
                float v3 = eluf(fmaf(ccv, wv0.w, bfhi(A[i].y) + bva.w));
                float v4 = eluf(fmaf(ccv, wv1.x, bflo(A[i].z) + bvb.x));
                float v5 = eluf(fmaf(ccv, wv1.y, bfhi(A[i].z) + bvb.y));
                float v6 = eluf(fmaf(ccv, wv1.z, bflo(A[i].w) + bvb.z));
                float v7 = eluf(fmaf(ccv, wv1.w, bfhi(A[i].w) + bvb.w));
                s[0] += v0; s[1] += v1; s[2] += v2; s[3] += v3;
                s[4] += v4; s[5] += v5; s[6] += v6; s[7] += v7;
                uint4 pk;
                pk.x = pk2(v0, v1); pk.y = pk2(v2, v3);
                pk.z = pk2(v4, v5); pk.w = pk2(v6, v7);
                *(uint4*)&x1t[c * LDAe + h0] = pk;
            }
            #pragma unroll
            for (int j = 0; j < 8; ++j) s[j] += __shfl_xor(s[j], 32);
            if (lane < 32) {
                float4 p0 = {s[0], s[1], s[2], s[3]};
                float4 p1 = {s[4], s[5], s[6], s[7]};
                *(float4*)&scratch[w * 258 + h0] = p0;
                *(float4*)&scratch[w * 258 + h0 + 4] = p1;
            }
        }
        __syncthreads();   // B1: x1t + pp complete

        // ===== MFMA: 4mt x 4nt, K=256 in 8 steps, B-frags double-buffered =====
        floatx4 acc[4][4];
        #pragma unroll
        for (int mt = 0; mt < 4; ++mt)
            #pragma unroll
            for (int nt = 0; nt < 4; ++nt)
                acc[mt][nt] = (floatx4){0.f, 0.f, 0.f, 0.f};

        #pragma unroll
        for (int kt = 0; kt < 8; ++kt) {
            short8 af[4];
            #pragma unroll
            for (int mt = 0; mt < 4; ++mt)
                af[mt] = *(const short8*)(abase + mt * 16 * LDAe + kt * 32);
            short8 bnx[4];
            if (kt < 7) {
                #pragma unroll
                for (int nt = 0; nt < 4; ++nt)
                    bnx[nt] = *(const short8*)(bbase + (size_t)nt * 16 * H_DIM + (kt + 1) * 32);
            }
            #pragma unroll
            for (int nt = 0; nt < 4; ++nt)
                #pragma unroll
                for (int mt = 0; mt < 4; ++mt)
                    acc[mt][nt] = __builtin_amdgcn_mfma_f32_16x16x32_bf16(af[mt], bcur[nt], acc[mt][nt], 0, 0, 0);
            if (kt < 7) {
                #pragma unroll
                for (int nt = 0; nt < 4; ++nt) bcur[nt] = bnx[nt];
            }
        }

        // ===== p-reduce =====
        if (t < H_DIM) {
            float ps = 0.f;
            #pragma unroll
            for (int w2 = 0; w2 < 8; ++w2) ps += scratch[w2 * 258 + t];
            pvec[t] = ps * (1.0f / 128.0f);
        }
        __syncthreads();   // B2: pvec ready; x1t/scratch reads done

        // ===== q = p @ W2b + b2 (bf16 w2bb, lane-coalesced, 2-way h-split) =====
        {
            const int j = t & 255, hf = t >> 8;
            const unsigned short* wp = w2bb + (size_t)(hf * 128) * H_DIM + j;
            const float* pv = pvec + hf * 128;
            float q0 = 0.f, q1 = 0.f, q2 = 0.f, q3 = 0.f;
            #pragma unroll 8
            for (int h = 0; h < 128; h += 4) {
                q0 = fmaf(pv[h + 0], bflo((unsigned)wp[(size_t)(h + 0) * H_DIM] << 16), q0);
                q1 = fmaf(pv[h + 1], bflo((unsigned)wp[(size_t)(h + 1) * H_DIM] << 16), q1);
                q2 = fmaf(pv[h + 2], bflo((unsigned)wp[(size_t)(h + 2) * H_DIM] << 16), q2);
                q3 = fmaf(pv[h + 3], bflo((unsigned)wp[(size_t)(h + 3) * H_DIM] << 16), q3);
            }
            const float qp = (q0 + q1) + (q2 + q3);
            if (hf) qtmp[j] = qp;
            __syncthreads();           // B3
            if (!hf) qv[j] = qp + qtmp[j] + g_b2[j];
        }
        __syncthreads();   // B4: qv ready

        // ===== epilogue: logit partials (C/D: col=lane&15, row=quad*4+reg) =====
        {
            float qj[4], w3j[4];
            #pragma unroll
            for (int nt = 0; nt < 4; ++nt) {
                const int j = wn * 64 + nt * 16 + nlo;
                qj[nt] = qv[j];
                w3j[nt] = w3v[j];
            }
            #pragma unroll
            for (int mt = 0; mt < 4; ++mt) {
                #pragma unroll
                for (int reg = 0; reg < 4; ++reg) {
                    float part = 0.f;
                    #pragma unroll
                    for (int nt = 0; nt < 4; ++nt)
                        part = fmaf(eluf(acc[mt][nt][reg] + qj[nt]), w3j[nt], part);
                    part += __shfl_xor(part, 1);
                    part += __shfl_xor(part, 2);
                    part += __shfl_xor(part, 4);
                    part += __shfl_xor(part, 8);
                    if (nlo == 0)
                        red2[(wm * 64 + mt * 16 + quad * 4 + reg) * 5 + wn] = part;
                }
            }
        }
        __syncthreads();   // B5: red2 complete

        // ===== softmax (no max-subtraction: logits ~ +-0.01, clamp for safety) =====
        float e = 0.f;
        if (t < C_CELLS) {
            float s = red2[t * 5 + 0] + red2[t * 5 + 1] + red2[t * 5 + 2] + red2[t * 5 + 3];
            e = __expf(fminf(s, 80.f));
            float S = e;
            #pragma unroll
            for (int off = 1; off < 64; off <<= 1) S += __shfl_xor(S, off);
            if (lane == 0) wred[w] = S;
        }
        __syncthreads();   // B6
        if (t < C_CELLS) out[(size_t)t * G_GENES + g0i + gg] = e / (wred[0] + wred[1]);

        // ===== prefetch gene 1 operands (acc dead; stores in flight) =====
        if (gg == 0) {
            #pragma unroll
            for (int i = 0; i < 8; ++i)
                A[i] = *(const uint4*)(Atcbf + (size_t)(cgrp * 8 + i) * H_DIM + h0);
            bva = *(const float4*)(Bvg + (size_t)(g0i + 1) * H_DIM + h0);
            bvb = *(const float4*)(Bvg + (size_t)(g0i + 1) * H_DIM + h0 + 4);
            #pragma unroll
            for (int nt = 0; nt < 4; ++nt)
                bcur[nt] = *(const short8*)(bbase + (size_t)nt * 16 * H_DIM);
        }
    }
}

// ---------------------------------------------------------------------------
extern "C" void kernel_launch(void* const* d_in, const int* in_sizes, int n_in,
                              void* d_out, int out_size, void* d_ws, size_t ws_size,
                              hipStream_t stream) {
    const float* ctrl   = (const float*)d_in[0];
    const float* shiftv = (const float*)d_in[1];
    const int*   gidx   = (const int*)d_in[2];
    const float* ce_w1  = (const float*)d_in[3];
    const float* ce_b1  = (const float*)d_in[4];
    const float* ce_w2  = (const float*)d_in[5];
    const float* ce_b2  = (const float*)d_in[6];
    const float* gtab   = (const float*)d_in[7];
    const float* g_w1   = (const float*)d_in[8];
    const float* g_b1   = (const float*)d_in[9];
    const float* g_w2   = (const float*)d_in[10];
    const float* g_b2   = (const float*)d_in[11];
    const float* g_w3   = (const float*)d_in[12];
    // g_b3 and the p2@w3b term are per-gene constants: cancel in softmax.

    // workspace: Atcbf 128K | w2abt 128K | w2bb 128K | Bvg 2M | hidpart 2M
    char* ws = (char*)d_ws;
    unsigned short* Atcbf = (unsigned short*)(ws);
    unsigned short* w2abt = (unsigned short*)(ws + 128 * 1024);
    unsigned short* w2bb  = (unsigned short*)(ws + 256 * 1024);
    float* Bvg            = (float*)(ws + 384 * 1024);
    float* hidpart        = (float*)(ws + 384 * 1024 + (size_t)G_GENES * H_DIM * 4);
    float* out            = (float*)d_out;

    k_g1<<<2056, 512, 0, stream>>>(
        ctrl, ce_w1, g_w1, g_b1, shiftv, gidx, gtab, g_w2, hidpart, w2abt, w2bb, Bvg);
    k_fin<<<C_CELLS, 256, 0, stream>>>(hidpart, ce_b1, ce_w2, ce_b2, g_w1, Atcbf);
    k_main<<<G_GENES / 2, 512, 0, stream>>>(ctrl, gidx, g_w1, g_b2, g_w3,
                                            Atcbf, Bvg, w2abt, w2bb, out);
}

// Round 13
// 206.077 us; speedup vs baseline: 1.2997x; 1.2997x over previous
//
#include <hip/hip_runtime.h>
#include <hip/hip_bf16.h>
#include <math.h>

#define G_GENES 2000
#define C_CELLS 128
#define H_DIM   256
#define CE_DIM  64
#define LDAe    260   // x1t row stride (bf16 elems): 130 dw = 2 mod 32 -> conflict-free

typedef __attribute__((ext_vector_type(8))) short short8;
typedef __attribute__((ext_vector_type(4))) float floatx4;

__device__ __forceinline__ float eluf(float x) {
    float e = __expf(x) - 1.0f;
    return x > 0.0f ? x : e;
}
__device__ __forceinline__ unsigned short f2bf(float v) {
    unsigned u = __float_as_uint(v);
    u += 0x7FFF + ((u >> 16) & 1);       // RNE
    return (unsigned short)(u >> 16);
}
__device__ __forceinline__ unsigned pk2(float a, float b) {   // v_cvt_pk_bf16_f32
    __hip_bfloat162 h2 = __float22bfloat162_rn(make_float2(a, b));
    unsigned r; __builtin_memcpy(&r, &h2, 4); return r;
}
__device__ __forceinline__ float bflo(unsigned u) { return __uint_as_float(u << 16); }
__device__ __forceinline__ float bfhi(unsigned u) { return __uint_as_float(u & 0xffff0000u); }
union U8 { unsigned u[4]; short8 s; uint4 v; };

// ---------------------------------------------------------------------------
// K_g1: 2056 blocks x 512 threads, four roles (unchanged from R10):
//  [0,1024):     fp32 split-K hid partials
//  [1024,1040):  w2abt[n][k] = bf16(g_w2[k][n]), k<256
//  [1040,1056):  w2bb[h][j]  = bf16(g_w2[256+h][j])
//  [1056,2056):  Bvg[g][h] per-gene bias row (2 genes/block)
// ---------------------------------------------------------------------------
__global__ __launch_bounds__(512) void k_g1(
    const float* __restrict__ ctrl, const float* __restrict__ ce_w1,
    const float* __restrict__ g_w1, const float* __restrict__ g_b1,
    const float* __restrict__ shiftv, const int* __restrict__ gidx,
    const float* __restrict__ gtab, const float* __restrict__ g_w2,
    float* __restrict__ hidpart, unsigned short* __restrict__ w2abt,
    unsigned short* __restrict__ w2bb, float* __restrict__ Bvg)
{
    const int b = blockIdx.x;
    const int t = threadIdx.x;

    if (b < 1024) {
        __shared__ float crow[2][128];
        const int cpair = b >> 4;
        const int kc    = b & 15;
        const int csub  = t >> 8;
        const int h     = t & 255;
        const int c     = cpair * 2 + csub;

        if (h < 125) crow[csub][h] = ctrl[(size_t)c * G_GENES + kc * 125 + h];
        __syncthreads();

        float s0 = 0.f, s1 = 0.f, s2 = 0.f, s3 = 0.f, s4 = 0.f;
        const float* w = ce_w1 + (size_t)(kc * 125) * H_DIM + h;
        const float* cr = crow[csub];
        #pragma unroll 5
        for (int k = 0; k < 125; k += 5) {
            s0 = fmaf(cr[k + 0], w[(size_t)(k + 0) * H_DIM], s0);
            s1 = fmaf(cr[k + 1], w[(size_t)(k + 1) * H_DIM], s1);
            s2 = fmaf(cr[k + 2], w[(size_t)(k + 2) * H_DIM], s2);
            s3 = fmaf(cr[k + 3], w[(size_t)(k + 3) * H_DIM], s3);
            s4 = fmaf(cr[k + 4], w[(size_t)(k + 4) * H_DIM], s4);
        }
        hidpart[((size_t)kc * C_CELLS + c) * H_DIM + h] = ((s0 + s1) + (s2 + s3)) + s4;
    } else if (b < 1040) {
        const int n  = (b - 1024) * 16 + (t >> 5);
        const int k0 = (t & 31) * 8;
        float v[8];
        #pragma unroll
        for (int j = 0; j < 8; ++j) v[j] = g_w2[(size_t)(k0 + j) * H_DIM + n];
        U8 u;
        u.u[0] = pk2(v[0], v[1]); u.u[1] = pk2(v[2], v[3]);
        u.u[2] = pk2(v[4], v[5]); u.u[3] = pk2(v[6], v[7]);
        *(uint4*)&w2abt[(size_t)n * H_DIM + k0] = u.v;
    } else if (b < 1056) {
        const int hr = (b - 1040) * 16 + (t >> 5);
        const int j0 = (t & 31) * 8;
        const float* src = g_w2 + (size_t)(H_DIM + hr) * H_DIM + j0;
        float4 f0 = *(const float4*)src;
        float4 f1 = *(const float4*)(src + 4);
        U8 u;
        u.u[0] = pk2(f0.x, f0.y); u.u[1] = pk2(f0.z, f0.w);
        u.u[2] = pk2(f1.x, f1.y); u.u[3] = pk2(f1.z, f1.w);
        *(uint4*)&w2bb[(size_t)hr * H_DIM + j0] = u.v;
    } else {
        const int g = (b - 1056) * 2 + (t >> 8);
        const int h = t & 255;
        const int idx = gidx[g];
        float bv = g_b1[h] + 128.0f * g_w1[(size_t)130 * H_DIM + h]
                 + shiftv[idx] * g_w1[(size_t)129 * H_DIM + h];
        #pragma unroll 8
        for (int e = 0; e < CE_DIM; ++e)
            bv = fmaf(gtab[(size_t)idx * CE_DIM + e], g_w1[(size_t)(65 + e) * H_DIM + h], bv);
        Bvg[(size_t)g * H_DIM + h] = bv;
    }
}

// ---------------------------------------------------------------------------
// K_fin: 128 blocks x 256 thr (unchanged from R10)
// ---------------------------------------------------------------------------
__global__ __launch_bounds__(256) void k_fin(
    const float* __restrict__ hidpart, const float* __restrict__ ce_b1,
    const float* __restrict__ ce_w2, const float* __restrict__ ce_b2,
    const float* __restrict__ g_w1, unsigned short* __restrict__ Atcbf)
{
    __shared__ float hid[H_DIM];
    __shared__ float celp[4 * CE_DIM];
    __shared__ float cel[CE_DIM];
    const int c = blockIdx.x;
    const int t = threadIdx.x;

    float s = ce_b1[t];
    #pragma unroll
    for (int kc = 0; kc < 16; ++kc)
        s += hidpart[((size_t)kc * C_CELLS + c) * H_DIM + t];
    hid[t] = eluf(s);
    __syncthreads();

    {
        const int e = t & 63, q4 = t >> 6;
        float cp = 0.f;
        #pragma unroll 8
        for (int hh = 0; hh < 64; ++hh)
            cp = fmaf(hid[q4 * 64 + hh], ce_w2[(size_t)(q4 * 64 + hh) * CE_DIM + e], cp);
        celp[q4 * CE_DIM + e] = cp;
    }
    __syncthreads();
    if (t < CE_DIM)
        cel[t] = ce_b2[t] + celp[t] + celp[CE_DIM + t] + celp[2 * CE_DIM + t] + celp[3 * CE_DIM + t];
    __syncthreads();

    float a = 0.f;
    #pragma unroll 8
    for (int e = 0; e < CE_DIM; ++e) a = fmaf(cel[e], g_w1[(size_t)(1 + e) * H_DIM + t], a);
    Atcbf[(size_t)c * H_DIM + t] = f2bf(a);
}

// ---------------------------------------------------------------------------
// K_main: one block per gene, 512 threads = 8 waves (2m x 4n wave grid).
// R10 structure exactly; tail-only edits: (1) q halves write qa/qb, merged
// in the epilogue with preloaded b2l (kills one barrier+phase); (2) softmax
// without max-subtraction (logits ~ +-0.3; clamped) kills another barrier.
// ---------------------------------------------------------------------------
__global__ __launch_bounds__(512, 4) void k_main(
    const float* __restrict__ ctrl, const int* __restrict__ gidx,
    const float* __restrict__ g_w1, const float* __restrict__ g_b2,
    const float* __restrict__ g_w3, const unsigned short* __restrict__ Atcbf,
    const float* __restrict__ Bvg, const unsigned short* __restrict__ w2abt,
    const unsigned short* __restrict__ w2bb, float* __restrict__ out)
{
    __shared__ __align__(16) unsigned short x1t[C_CELLS * LDAe];  // 66560 B
    __shared__ __align__(16) float scratch[8 * 258];              // pp -> red2
    __shared__ float pvec[H_DIM];
    __shared__ float qa[H_DIM];
    __shared__ float qb[H_DIM];
    __shared__ float b2l[H_DIM];
    __shared__ float w3v[H_DIM];
    __shared__ float cc[C_CELLS];
    __shared__ float wred[2];

    const int g = blockIdx.x;
    const int t = threadIdx.x;
    const int idx = gidx[g];

    const int lane = t & 63;
    const int w    = t >> 6;
    const int quad = lane >> 4;
    const int nlo  = lane & 15;
    const int wm   = w >> 2;
    const int wn   = w & 3;

    // ---- pre-B0 global prefetches (all independent; land during B0 wait) ----
    const int ho = t & 31, cgrp = t >> 5;
    const int h0 = ho * 8;
    uint4 A[8];                    // 8 rows x 8 bf16 Atc values (32 VGPRs)
    #pragma unroll
    for (int i = 0; i < 8; ++i)
        A[i] = *(const uint4*)(Atcbf + (size_t)(cgrp * 8 + i) * H_DIM + h0);
    float4 bv0 = *(const float4*)(Bvg + (size_t)g * H_DIM + h0);
    float4 bv1 = *(const float4*)(Bvg + (size_t)g * H_DIM + h0 + 4);
    float4 wv0 = *(const float4*)(g_w1 + h0);
    float4 wv1 = *(const float4*)(g_w1 + h0 + 4);

    const unsigned short* bbase = w2abt + (size_t)(wn * 64 + nlo) * H_DIM + quad * 8;
    short8 bcur[4];
    #pragma unroll
    for (int nt = 0; nt < 4; ++nt)
        bcur[nt] = *(const short8*)(bbase + (size_t)nt * 16 * H_DIM);

    if (t < C_CELLS) cc[t] = ctrl[(size_t)t * G_GENES + idx];
    if (t < H_DIM) {
        w3v[t] = g_w3[t];
        b2l[t] = g_b2[t];
    }
    __syncthreads();   // B0: cc/w3v/b2l ready

    {   // ---- x1 build (+ register p-partials) ----
        float s[8];
        #pragma unroll
        for (int j = 0; j < 8; ++j) s[j] = 0.f;
        #pragma unroll
        for (int i = 0; i < 8; ++i) {
            const int c = cgrp * 8 + i;
            const float ccv = cc[c];
            float v0 = eluf(fmaf(ccv, wv0.x, bflo(A[i].x) + bv0.x));
            float v1 = eluf(fmaf(ccv, wv0.y, bfhi(A[i].x) + bv0.y));
            float v2 = eluf(fmaf(ccv, wv0.z, bflo(A[i].y) + bv0.z));
            float v3 = eluf(fmaf(ccv, wv0.w, bfhi(A[i].y) + bv0.w));
            float v4 = eluf(fmaf(ccv, wv1.x, bflo(A[i].z) + bv1.x));
            float v5 = eluf(fmaf(ccv, wv1.y, bfhi(A[i].z) + bv1.y));
            float v6 = eluf(fmaf(ccv, wv1.z, bflo(A[i].w) + bv1.z));
            float v7 = eluf(fmaf(ccv, wv1.w, bfhi(A[i].w) + bv1.w));
            s[0] += v0; s[1] += v1; s[2] += v2; s[3] += v3;
            s[4] += v4; s[5] += v5; s[6] += v6; s[7] += v7;
            uint4 pk;
            pk.x = pk2(v0, v1); pk.y = pk2(v2, v3);
            pk.z = pk2(v4, v5); pk.w = pk2(v6, v7);
            *(uint4*)&x1t[c * LDAe + h0] = pk;
        }
        #pragma unroll
        for (int j = 0; j < 8; ++j) s[j] += __shfl_xor(s[j], 32);
        if (lane < 32) {
            float4 p0 = {s[0], s[1], s[2], s[3]};
            float4 p1 = {s[4], s[5], s[6], s[7]};
            *(float4*)&scratch[w * 258 + h0] = p0;
            *(float4*)&scratch[w * 258 + h0 + 4] = p1;
        }
    }
    __syncthreads();   // B1: x1t + pp complete

    // ---- MFMA: 4mt x 4nt, K=256 in 8 steps, B-frags double-buffered ----
    floatx4 acc[4][4];
    #pragma unroll
    for (int mt = 0; mt < 4; ++mt)
        #pragma unroll
        for (int nt = 0; nt < 4; ++nt)
            acc[mt][nt] = (floatx4){0.f, 0.f, 0.f, 0.f};

    const unsigned short* abase = &x1t[(wm * 64 + nlo) * LDAe + quad * 8];

    #pragma unroll
    for (int kt = 0; kt < 8; ++kt) {
        short8 af[4];
        #pragma unroll
        for (int mt = 0; mt < 4; ++mt)
            af[mt] = *(const short8*)(abase + mt * 16 * LDAe + kt * 32);
        short8 bnx[4];
        if (kt < 7) {
            #pragma unroll
            for (int nt = 0; nt < 4; ++nt)
                bnx[nt] = *(const short8*)(bbase + (size_t)nt * 16 * H_DIM + (kt + 1) * 32);
        }
        #pragma unroll
        for (int nt = 0; nt < 4; ++nt)
            #pragma unroll
            for (int mt = 0; mt < 4; ++mt)
                acc[mt][nt] = __builtin_amdgcn_mfma_f32_16x16x32_bf16(af[mt], bcur[nt], acc[mt][nt], 0, 0, 0);
        if (kt < 7) {
            #pragma unroll
            for (int nt = 0; nt < 4; ++nt) bcur[nt] = bnx[nt];
        }
    }

    // ---- p-reduce into pvec ----
    if (t < H_DIM) {
        float ps = 0.f;
        #pragma unroll
        for (int w2 = 0; w2 < 8; ++w2) ps += scratch[w2 * 258 + t];
        pvec[t] = ps * (1.0f / 128.0f);
    }
    __syncthreads();   // B2: pvec ready

    // ---- q halves: qa (h<128), qb (h>=128); no merge barrier needed ----
    {
        const int j = t & 255, hf = t >> 8;
        const unsigned short* wp = w2bb + (size_t)(hf * 128) * H_DIM + j;
        const float* pv = pvec + hf * 128;
        float q0 = 0.f, q1 = 0.f, q2 = 0.f, q3 = 0.f;
        #pragma unroll 8
        for (int h = 0; h < 128; h += 4) {
            q0 = fmaf(pv[h + 0], bflo((unsigned)wp[(size_t)(h + 0) * H_DIM] << 16), q0);
            q1 = fmaf(pv[h + 1], bflo((unsigned)wp[(size_t)(h + 1) * H_DIM] << 16), q1);
            q2 = fmaf(pv[h + 2], bflo((unsigned)wp[(size_t)(h + 2) * H_DIM] << 16), q2);
            q3 = fmaf(pv[h + 3], bflo((unsigned)wp[(size_t)(h + 3) * H_DIM] << 16), q3);
        }
        const float qp = (q0 + q1) + (q2 + q3);
        if (hf) qb[j] = qp; else qa[j] = qp;
    }
    __syncthreads();   // B3: qa/qb ready

    // ---- epilogue: logit partials (C/D: col=lane&15, row=quad*4+reg) ----
    float* red2 = scratch;
    float qj[4], w3j[4];
    #pragma unroll
    for (int nt = 0; nt < 4; ++nt) {
        const int j = wn * 64 + nt * 16 + nlo;
        qj[nt] = qa[j] + qb[j] + b2l[j];
        w3j[nt] = w3v[j];
    }
    #pragma unroll
    for (int mt = 0; mt < 4; ++mt) {
        #pragma unroll
        for (int reg = 0; reg < 4; ++reg) {
            float part = 0.f;
            #pragma unroll
            for (int nt = 0; nt < 4; ++nt)
                part = fmaf(eluf(acc[mt][nt][reg] + qj[nt]), w3j[nt], part);
            part += __shfl_xor(part, 1);
            part += __shfl_xor(part, 2);
            part += __shfl_xor(part, 4);
            part += __shfl_xor(part, 8);
            if (nlo == 0)
                red2[(wm * 64 + mt * 16 + quad * 4 + reg) * 5 + wn] = part;
        }
    }
    __syncthreads();   // B4: red2 complete

    // ---- softmax (no max-subtraction: logits ~ +-0.3, clamp for safety) ----
    float e = 0.f;
    if (t < C_CELLS) {
        float s = red2[t * 5 + 0] + red2[t * 5 + 1] + red2[t * 5 + 2] + red2[t * 5 + 3];
        e = __expf(fminf(s, 80.f));
        float S = e;
        #pragma unroll
        for (int off = 1; off < 64; off <<= 1) S += __shfl_xor(S, off);
        if (lane == 0) wred[w] = S;
    }
    __syncthreads();   // B5
    if (t < C_CELLS) out[(size_t)t * G_GENES + g] = e / (wred[0] + wred[1]);
}

// ---------------------------------------------------------------------------
extern "C" void kernel_launch(void* const* d_in, const int* in_sizes, int n_in,
                              void* d_out, int out_size, void* d_ws, size_t ws_size,
                              hipStream_t stream) {
    const float* ctrl   = (const float*)d_in[0];
    const float* shiftv = (const float*)d_in[1];
    const int*   gidx   = (const int*)d_in[2];
    const float* ce_w1  = (const float*)d_in[3];
    const float* ce_b1  = (const float*)d_in[4];
    const float* ce_w2  = (const float*)d_in[5];
    const float* ce_b2  = (const float*)d_in[6];
    const float* gtab   = (const float*)d_in[7];
    const float* g_w1   = (const float*)d_in[8];
    const float* g_b1   = (const float*)d_in[9];
    const float* g_w2   = (const float*)d_in[10];
    const float* g_b2   = (const float*)d_in[11];
    const float* g_w3   = (const float*)d_in[12];
    // g_b3 and the p2@w3b term are per-gene constants: cancel in softmax.

    // workspace: Atcbf 128K | w2abt 128K | w2bb 128K | Bvg 2M | hidpart 2M
    char* ws = (char*)d_ws;
    unsigned short* Atcbf = (unsigned short*)(ws);
    unsigned short* w2abt = (unsigned short*)(ws + 128 * 1024);
    unsigned short* w2bb  = (unsigned short*)(ws + 256 * 1024);
    float* Bvg            = (float*)(ws + 384 * 1024);
    float* hidpart        = (float*)(ws + 384 * 1024 + (size_t)G_GENES * H_DIM * 4);
    float* out            = (float*)d_out;

    k_g1<<<2056, 512, 0, stream>>>(
        ctrl, ce_w1, g_w1, g_b1, shiftv, gidx, gtab, g_w2, hidpart, w2abt, w2bb, Bvg);
    k_fin<<<C_CELLS, 256, 0, stream>>>(hidpart, ce_b1, ce_w2, ce_b2, g_w1, Atcbf);
    k_main<<<G_GENES, 512, 0, stream>>>(ctrl, gidx, g_w1, g_b2, g_w3,
                                        Atcbf, Bvg, w2abt, w2bb, out);
}